// Round 4
// baseline (220.444 us; speedup 1.0000x reference)
//
#include <hip/hip_runtime.h>

#define H 1024
#define W 1024
#define NPIX (H*W)
#define BATCH 4
#define SH 4          // output rows per strip
#define SLOTS 32
#define PART_FLOATS (BATCH*15*SLOTS)

struct Raw {          // one staged input row (per-lane 4 px + edge col)
  float4 X0, X1, X2;  // x[row][c0..c0+3][0..2] interleaved
  float4 F0, F1, F2;  // fhigh planes 0..2, cols c0..c0+3
  float4 XE;          // edge x pixels (lane0: col c0-1 in .yzw ; lane63: col c0+4 in .xyz)
  float  FE0, FE1, FE2; // edge fhigh per plane
};

struct RawX {
  float4 X0, X1, X2, XE;
};

__global__ __launch_bounds__(64) void pass1(
    const float* __restrict__ x, const float* __restrict__ fhigh,
    const float* __restrict__ qCw, const float* __restrict__ qdw,
    const float* __restrict__ kCw, const float* __restrict__ kdw,
    float* __restrict__ partials)
{
  const int l  = threadIdx.x;          // lane 0..63
  const int bx = blockIdx.x;           // seg + 4*strip
  const int b  = blockIdx.y;
  const int seg = bx & 3;
  const int r0  = (bx >> 2) * SH;
  const int c0  = seg * 256 + l * 4;
  const bool eL = (l == 0)  && (c0 > 0);
  const bool eR = (l == 63) && (c0 + 4 < W);

  float wqc[9], wkc[9], wqd[27], wkd[27];
  #pragma unroll
  for (int i = 0; i < 9; i++)  { wqc[i] = qCw[i]; wkc[i] = kCw[i]; }
  #pragma unroll
  for (int i = 0; i < 27; i++) { wqd[i] = qdw[i]; wkd[i] = kdw[i]; }

  const float* xb = x     + (size_t)b * NPIX * 3;
  const float* fb = fhigh + (size_t)b * 3 * NPIX;

  float qmid[3][3][4], kmid[3][3][4];  // [phase][ch][px]
  float qe[3][3], ke[3][3];            // [phase][ch] edge-col mids (lane0=left, lane63=right)
  float acc[15];
  #pragma unroll
  for (int i = 0; i < 15; i++) acc[i] = 0.f;

  Raw A, B2;

  auto LOAD = [&](Raw& S, int r) {
    const float4 z4 = {0.f, 0.f, 0.f, 0.f};
    S.X0 = z4; S.X1 = z4; S.X2 = z4; S.F0 = z4; S.F1 = z4; S.F2 = z4; S.XE = z4;
    S.FE0 = 0.f; S.FE1 = 0.f; S.FE2 = 0.f;
    if ((unsigned)r < (unsigned)H) {
      const float* xr = xb + (size_t)r * (W * 3);
      const float* fr = fb + (size_t)r * W;
      S.X0 = *(const float4*)(xr + c0 * 3);
      S.X1 = *(const float4*)(xr + c0 * 3 + 4);
      S.X2 = *(const float4*)(xr + c0 * 3 + 8);
      S.F0 = *(const float4*)(fr + c0);
      S.F1 = *(const float4*)(fr + NPIX + c0);
      S.F2 = *(const float4*)(fr + 2 * NPIX + c0);
      if (eL) {
        S.XE  = *(const float4*)(xr + (c0 - 4) * 3 + 8);
        S.FE0 = fr[c0 - 1]; S.FE1 = fr[NPIX + c0 - 1]; S.FE2 = fr[2 * NPIX + c0 - 1];
      } else if (eR) {
        S.XE  = *(const float4*)(xr + (c0 + 4) * 3);
        S.FE0 = fr[c0 + 4]; S.FE1 = fr[NPIX + c0 + 4]; S.FE2 = fr[2 * NPIX + c0 + 4];
      }
    }
  };

  auto MID = [&](const Raw& S, int P) {
    float xc0[4] = {S.X0.x, S.X0.w, S.X1.z, S.X2.y};
    float xc1[4] = {S.X0.y, S.X1.x, S.X1.w, S.X2.z};
    float xc2[4] = {S.X0.z, S.X1.y, S.X2.x, S.X2.w};
    float fc0[4] = {S.F0.x, S.F0.y, S.F0.z, S.F0.w};
    float fc1[4] = {S.F1.x, S.F1.y, S.F1.z, S.F1.w};
    float fc2[4] = {S.F2.x, S.F2.y, S.F2.z, S.F2.w};
    #pragma unroll
    for (int c = 0; c < 3; c++) {
      #pragma unroll
      for (int i = 0; i < 4; i++) {
        kmid[P][c][i] = wkc[c*3+0]*xc0[i] + wkc[c*3+1]*xc1[i] + wkc[c*3+2]*xc2[i];
        qmid[P][c][i] = wqc[c*3+0]*fc0[i] + wqc[c*3+1]*fc1[i] + wqc[c*3+2]*fc2[i];
      }
    }
    float ex0 = eL ? S.XE.y : S.XE.x;
    float ex1 = eL ? S.XE.z : S.XE.y;
    float ex2 = eL ? S.XE.w : S.XE.z;
    #pragma unroll
    for (int c = 0; c < 3; c++) {
      ke[P][c] = wkc[c*3+0]*ex0 + wkc[c*3+1]*ex1 + wkc[c*3+2]*ex2;
      qe[P][c] = wqc[c*3+0]*S.FE0 + wqc[c*3+1]*S.FE1 + wqc[c*3+2]*S.FE2;
    }
  };

  auto CONS = [&](int j) {
    float qv[3][4], kv[3][4];
    #pragma unroll
    for (int c = 0; c < 3; c++)
      #pragma unroll
      for (int i = 0; i < 4; i++) { qv[c][i] = 0.f; kv[c][i] = 0.f; }
    #pragma unroll
    for (int dy = 0; dy < 3; dy++) {
      const int P = (j + dy) % 3;
      #pragma unroll
      for (int c = 0; c < 3; c++) {
        {
          float m0 = qmid[P][c][0], m1 = qmid[P][c][1], m2 = qmid[P][c][2], m3 = qmid[P][c][3];
          float ml = __shfl_up(m3, 1, 64);   ml = (l == 0)  ? qe[P][c] : ml;
          float mr = __shfl_down(m0, 1, 64); mr = (l == 63) ? qe[P][c] : mr;
          float w0 = wqd[c*9+dy*3+0], w1 = wqd[c*9+dy*3+1], w2 = wqd[c*9+dy*3+2];
          qv[c][0] += w0*ml + w1*m0 + w2*m1;
          qv[c][1] += w0*m0 + w1*m1 + w2*m2;
          qv[c][2] += w0*m1 + w1*m2 + w2*m3;
          qv[c][3] += w0*m2 + w1*m3 + w2*mr;
        }
        {
          float m0 = kmid[P][c][0], m1 = kmid[P][c][1], m2 = kmid[P][c][2], m3 = kmid[P][c][3];
          float ml = __shfl_up(m3, 1, 64);   ml = (l == 0)  ? ke[P][c] : ml;
          float mr = __shfl_down(m0, 1, 64); mr = (l == 63) ? ke[P][c] : mr;
          float w0 = wkd[c*9+dy*3+0], w1 = wkd[c*9+dy*3+1], w2 = wkd[c*9+dy*3+2];
          kv[c][0] += w0*ml + w1*m0 + w2*m1;
          kv[c][1] += w0*m0 + w1*m1 + w2*m2;
          kv[c][2] += w0*m1 + w1*m2 + w2*m3;
          kv[c][3] += w0*m2 + w1*m3 + w2*mr;
        }
      }
    }
    #pragma unroll
    for (int i = 0; i < 4; i++) {
      #pragma unroll
      for (int c = 0; c < 3; c++) { acc[c] += qv[c][i]*qv[c][i]; acc[3+c] += kv[c][i]*kv[c][i]; }
      #pragma unroll
      for (int c = 0; c < 3; c++)
        #pragma unroll
        for (int d = 0; d < 3; d++) acc[6 + c*3 + d] += qv[c][i]*kv[d][i];
    }
  };

  // software-pipelined schedule: loads issued ~1 consume ahead of use
  LOAD(A,  r0 - 1);
  LOAD(B2, r0);
  MID(A, 0);
  LOAD(A,  r0 + 1);
  MID(B2, 1);
  LOAD(B2, r0 + 2);
  MID(A, 2);
  CONS(0);
  LOAD(A,  r0 + 3);
  MID(B2, 0);
  CONS(1);
  LOAD(B2, r0 + 4);
  MID(A, 1);
  CONS(2);
  MID(B2, 2);
  CONS(3);

  #pragma unroll
  for (int off = 32; off >= 1; off >>= 1)
    #pragma unroll
    for (int i = 0; i < 15; i++)
      acc[i] += __shfl_xor(acc[i], off, 64);

  if (l == 0) {
    const int slot = bx & (SLOTS - 1);
    #pragma unroll
    for (int i = 0; i < 15; i++)
      atomicAdd(&partials[(b * 15 + i) * SLOTS + slot], acc[i]);
  }
}

__global__ __launch_bounds__(64) void pass3(
    const float* __restrict__ x,
    const float* __restrict__ kCw, const float* __restrict__ kdw,
    const float* __restrict__ partials,
    const float* __restrict__ proj_w, const float* __restrict__ proj_b,
    const float* __restrict__ temperature,
    float* __restrict__ out)
{
  const int l  = threadIdx.x;
  const int bx = blockIdx.x;
  const int b  = blockIdx.y;
  const int seg = bx & 3;
  const int r0  = (bx >> 2) * SH;
  const int c0  = seg * 256 + l * 4;
  const bool eL = (l == 0)  && (c0 > 0);
  const bool eR = (l == 63) && (c0 + 4 < W);

  // ---- folded pass2: per-block uniform M = proj_w @ softmax(attn) ----
  float sums[15];
  #pragma unroll
  for (int i = 0; i < 15; i++) {
    float s = 0.f;
    #pragma unroll 8
    for (int sl = 0; sl < SLOTS; sl++) s += partials[(b * 15 + i) * SLOTS + sl];
    sums[i] = s;
  }
  float qn[3], kn[3];
  #pragma unroll
  for (int c = 0; c < 3; c++) { qn[c] = sqrtf(sums[c]); kn[c] = sqrtf(sums[3 + c]); }
  const float t = temperature[0];
  float attn[3][3];
  #pragma unroll
  for (int c = 0; c < 3; c++) {
    float lg[3];
    #pragma unroll
    for (int d = 0; d < 3; d++)
      lg[d] = sums[6 + c*3 + d] / fmaxf(qn[c], 1e-12f) / fmaxf(kn[d], 1e-12f) * t;
    float mx = fmaxf(lg[0], fmaxf(lg[1], lg[2]));
    float e0 = expf(lg[0] - mx), e1 = expf(lg[1] - mx), e2 = expf(lg[2] - mx);
    float inv = 1.f / (e0 + e1 + e2);
    attn[c][0] = e0 * inv; attn[c][1] = e1 * inv; attn[c][2] = e2 * inv;
  }
  float m[3][3];
  #pragma unroll
  for (int o = 0; o < 3; o++)
    #pragma unroll
    for (int d = 0; d < 3; d++)
      m[o][d] = proj_w[o*3+0]*attn[0][d] + proj_w[o*3+1]*attn[1][d] + proj_w[o*3+2]*attn[2][d];
  float pb[3] = {proj_b[0], proj_b[1], proj_b[2]};

  float wkc[9], wkd[27];
  #pragma unroll
  for (int i = 0; i < 9; i++)  wkc[i] = kCw[i];
  #pragma unroll
  for (int i = 0; i < 27; i++) wkd[i] = kdw[i];

  const float* xb = x + (size_t)b * NPIX * 3;
  float* ob = out + (size_t)b * NPIX * 3;

  float kmid[3][3][4], ke[3][3];
  RawX A, B2;

  auto LOAD = [&](RawX& S, int r) {
    const float4 z4 = {0.f, 0.f, 0.f, 0.f};
    S.X0 = z4; S.X1 = z4; S.X2 = z4; S.XE = z4;
    if ((unsigned)r < (unsigned)H) {
      const float* xr = xb + (size_t)r * (W * 3);
      S.X0 = *(const float4*)(xr + c0 * 3);
      S.X1 = *(const float4*)(xr + c0 * 3 + 4);
      S.X2 = *(const float4*)(xr + c0 * 3 + 8);
      if (eL)      S.XE = *(const float4*)(xr + (c0 - 4) * 3 + 8);
      else if (eR) S.XE = *(const float4*)(xr + (c0 + 4) * 3);
    }
  };

  auto MID = [&](const RawX& S, int P) {
    float xc0[4] = {S.X0.x, S.X0.w, S.X1.z, S.X2.y};
    float xc1[4] = {S.X0.y, S.X1.x, S.X1.w, S.X2.z};
    float xc2[4] = {S.X0.z, S.X1.y, S.X2.x, S.X2.w};
    #pragma unroll
    for (int c = 0; c < 3; c++)
      #pragma unroll
      for (int i = 0; i < 4; i++)
        kmid[P][c][i] = wkc[c*3+0]*xc0[i] + wkc[c*3+1]*xc1[i] + wkc[c*3+2]*xc2[i];
    float ex0 = eL ? S.XE.y : S.XE.x;
    float ex1 = eL ? S.XE.z : S.XE.y;
    float ex2 = eL ? S.XE.w : S.XE.z;
    #pragma unroll
    for (int c = 0; c < 3; c++)
      ke[P][c] = wkc[c*3+0]*ex0 + wkc[c*3+1]*ex1 + wkc[c*3+2]*ex2;
  };

  auto CONS = [&](int j) {
    float kv[3][4];
    #pragma unroll
    for (int c = 0; c < 3; c++)
      #pragma unroll
      for (int i = 0; i < 4; i++) kv[c][i] = 0.f;
    #pragma unroll
    for (int dy = 0; dy < 3; dy++) {
      const int P = (j + dy) % 3;
      #pragma unroll
      for (int c = 0; c < 3; c++) {
        float m0 = kmid[P][c][0], m1 = kmid[P][c][1], m2 = kmid[P][c][2], m3 = kmid[P][c][3];
        float ml = __shfl_up(m3, 1, 64);   ml = (l == 0)  ? ke[P][c] : ml;
        float mr = __shfl_down(m0, 1, 64); mr = (l == 63) ? ke[P][c] : mr;
        float w0 = wkd[c*9+dy*3+0], w1 = wkd[c*9+dy*3+1], w2 = wkd[c*9+dy*3+2];
        kv[c][0] += w0*ml + w1*m0 + w2*m1;
        kv[c][1] += w0*m0 + w1*m1 + w2*m2;
        kv[c][2] += w0*m1 + w1*m2 + w2*m3;
        kv[c][3] += w0*m2 + w1*m3 + w2*mr;
      }
    }
    float o[4][3];
    #pragma unroll
    for (int i = 0; i < 4; i++)
      #pragma unroll
      for (int oc = 0; oc < 3; oc++)
        o[i][oc] = m[oc][0]*kv[0][i] + m[oc][1]*kv[1][i] + m[oc][2]*kv[2][i] + pb[oc];
    float* orow = ob + ((size_t)(r0 + j) * W + c0) * 3;
    float4 w0, w1, w2;
    w0.x = o[0][0]; w0.y = o[0][1]; w0.z = o[0][2]; w0.w = o[1][0];
    w1.x = o[1][1]; w1.y = o[1][2]; w1.z = o[2][0]; w1.w = o[2][1];
    w2.x = o[2][2]; w2.y = o[3][0]; w2.z = o[3][1]; w2.w = o[3][2];
    *(float4*)(orow)     = w0;
    *(float4*)(orow + 4) = w1;
    *(float4*)(orow + 8) = w2;
  };

  LOAD(A,  r0 - 1);
  LOAD(B2, r0);
  MID(A, 0);
  LOAD(A,  r0 + 1);
  MID(B2, 1);
  LOAD(B2, r0 + 2);
  MID(A, 2);
  CONS(0);
  LOAD(A,  r0 + 3);
  MID(B2, 0);
  CONS(1);
  LOAD(B2, r0 + 4);
  MID(A, 1);
  CONS(2);
  MID(B2, 2);
  CONS(3);
}

extern "C" void kernel_launch(void* const* d_in, const int* in_sizes, int n_in,
                              void* d_out, int out_size, void* d_ws, size_t ws_size,
                              hipStream_t stream) {
  const float* x     = (const float*)d_in[0];
  const float* fhigh = (const float*)d_in[1];
  const float* qCw   = (const float*)d_in[2];
  const float* qdw   = (const float*)d_in[3];
  const float* kCw   = (const float*)d_in[4];
  const float* kdw   = (const float*)d_in[5];
  const float* pw    = (const float*)d_in[6];
  const float* pb    = (const float*)d_in[7];
  const float* temp  = (const float*)d_in[8];
  float* out = (float*)d_out;

  float* partials = (float*)d_ws;
  hipMemsetAsync(partials, 0, PART_FLOATS * sizeof(float), stream);

  dim3 grid(4 * (H / SH), BATCH);   // 1024 x 4 blocks of one wave each
  pass1<<<grid, 64, 0, stream>>>(x, fhigh, qCw, qdw, kCw, kdw, partials);
  pass3<<<grid, 64, 0, stream>>>(x, kCw, kdw, partials, pw, pb, temp, out);
}